// Round 6
// baseline (1851.018 us; speedup 1.0000x reference)
//
#include <hip/hip_runtime.h>

#define TOK 4096
#define HD 1024
#define ID 4096
#define NE 8
#define LS 72   // gemm2 LDS row stride in shorts

typedef __attribute__((ext_vector_type(4))) float f32x4;
typedef __attribute__((ext_vector_type(8))) __bf16 bf16x8;
typedef __attribute__((ext_vector_type(8))) unsigned short u16x8;

// gemm1 LDS: 128B rows, 8x16B slots, XOR swizzle (same involution on write+read)
#define AADDR(r, s) (((r) * 128) + ((((s) ^ ((r) & 7))) << 4))
#define BADDR(r, s) (65536 + ((r) * 128) + ((((s) ^ ((r) & 7))) << 4))

// compiler emits v_cvt_pk_bf16_f32 (RNE) for scalar casts -- do NOT hand-roll (m240)
__device__ __forceinline__ bf16x8 pack8(f32x4 a, f32x4 b) {
  bf16x8 r;
#pragma unroll
  for (int i = 0; i < 4; ++i) { r[i] = (__bf16)a[i]; r[i + 4] = (__bf16)b[i]; }
  return r;
}

__device__ __forceinline__ float gelu_tanh(float g) {
  float z = 0.7978845608028654f * (g + 0.044715f * g * g * g);
  float t = __expf(-2.0f * z);
  return g / (1.0f + t);
}

// barrier that does NOT drain vmcnt: LDS ordering via lgkmcnt(0), global prefetch stays in flight
__device__ __forceinline__ void bar_lgkm() {
  asm volatile("s_waitcnt lgkmcnt(0)" ::: "memory");
  __builtin_amdgcn_s_barrier();
}

__global__ void init_k(int* __restrict__ meta) {
  if (threadIdx.x < 16) meta[threadIdx.x] = 0;
}

// one wave per token: fp32 logits (argmax must match numpy fp32), top1 via first-max
__global__ void router_k(const float* __restrict__ x, const float* __restrict__ gw,
                         float* __restrict__ logits, int* __restrict__ top1) {
  const int wid = threadIdx.x >> 6;
  const int lane = threadIdx.x & 63;
  const int t = blockIdx.x * 4 + wid;
  const float* xr = x + (size_t)t * HD;
  float acc[NE];
#pragma unroll
  for (int e = 0; e < NE; ++e) acc[e] = 0.0f;
#pragma unroll
  for (int c = 0; c < 4; ++c) {
    const int k = (c * 64 + lane) * 4;
    f32x4 xv = *(const f32x4*)(xr + k);
#pragma unroll
    for (int e = 0; e < NE; ++e) {
      f32x4 gv = *(const f32x4*)(gw + e * HD + k);
      acc[e] += xv[0] * gv[0] + xv[1] * gv[1] + xv[2] * gv[2] + xv[3] * gv[3];
    }
  }
#pragma unroll
  for (int off = 32; off > 0; off >>= 1) {
#pragma unroll
    for (int e = 0; e < NE; ++e) acc[e] += __shfl_xor(acc[e], off, 64);
  }
  if (lane == 0) {
    int best = 0; float bv = acc[0];
#pragma unroll
    for (int e = 1; e < NE; ++e) if (acc[e] > bv) { bv = acc[e]; best = e; }
    top1[t] = best;
#pragma unroll
    for (int e = 0; e < NE; ++e) logits[(size_t)t * NE + e] = acc[e];
  }
}

__global__ void hist_k(const int* __restrict__ top1, int* __restrict__ counts) {
  int t = blockIdx.x * 256 + threadIdx.x;
  atomicAdd(&counts[top1[t]], 1);
}

__global__ void offsets_k(const int* __restrict__ counts, int* __restrict__ offsets) {
  if (threadIdx.x == 0) {
    int s = 0;
    for (int e = 0; e < NE; ++e) { offsets[e] = s; s += counts[e]; }
  }
}

__global__ void scatter_k(const int* __restrict__ top1, const int* __restrict__ offsets,
                          int* __restrict__ counts2, int* __restrict__ perm) {
  int t = blockIdx.x * 256 + threadIdx.x;
  int e = top1[t];
  int slot = atomicAdd(&counts2[e], 1);
  perm[offsets[e] + slot] = t;
}

// compact permuted bf16 copy of x: xp[p,:] = bf16(x[perm[p],:])
__global__ void xp_k(const float* __restrict__ x, const int* __restrict__ perm,
                     unsigned short* __restrict__ xp) {
  const int p = blockIdx.x * 4 + (threadIdx.x >> 6);
  const int lane = threadIdx.x & 63;
  const float* src = x + (size_t)perm[p] * HD + lane * 16;
  unsigned short* dst = xp + (size_t)p * HD + lane * 16;
  f32x4 v0 = *(const f32x4*)(src);
  f32x4 v1 = *(const f32x4*)(src + 4);
  f32x4 v2 = *(const f32x4*)(src + 8);
  f32x4 v3 = *(const f32x4*)(src + 12);
  *(bf16x8*)(dst) = pack8(v0, v1);
  *(bf16x8*)(dst + 8) = pack8(v2, v3);
}

// gemm1: hidden[p, nt*128+c] = gelu(xp[p] . wg[e][nt*128+c]) * (xp[p] . wu[e][nt*128+c])
// BM=512 (whole expert), N=128 shared gate+up, BK=64. 1024 thr = 16 waves (8wm x 2wn),
// each wave computes BOTH gate and up for its 64x64 patch -> lane-local gelu fusion.
// Weights pulled exactly once per block (line-perfect 128B rows). 96KB LDS single-buf,
// register prefetch dist-1, non-draining barriers.
__global__ __launch_bounds__(1024) void gemm1_k(
    const unsigned short* __restrict__ xp, const float* __restrict__ wg,
    const float* __restrict__ wu, const int* __restrict__ counts,
    const int* __restrict__ offsets, unsigned short* __restrict__ hidden) {
  const int e = blockIdx.z, mt = blockIdx.y, nt = blockIdx.x;
  const int ne = counts[e];
  if (mt * 512 >= ne) return;
  const int off = offsets[e];

  __shared__ __align__(16) char lds[98304];  // A [512][128B] @0, B [256][128B] @65536

  const int tid = threadIdx.x;
  const int lane = tid & 63;
  const int wid = tid >> 6;          // 0..15
  const int wm = wid >> 1;           // 0..7 -> M 64-chunk
  const int wn = wid & 1;            // 0..1 -> N 64-chunk
  const int frow = lane & 15;
  const int fk = lane >> 4;          // 0..3

  // A staging: 2 thr/row, 32 bf16 elems (64B) each, contiguous
  const int sra = tid >> 1;
  const int sba = (tid & 1) * 4;     // slot base (4 slots of 16B)
  int xrow = off + mt * 512 + sra;
  if (xrow >= TOK) xrow = TOK - 1;   // clamp; rows >= ne masked at store
  const unsigned short* asrc = xp + (size_t)xrow * HD + (tid & 1) * 32;

  // B staging: 4 thr/row, 16 fp32 (64B) each; rows 0-127 gate, 128-255 up. 128B/row = 1 line.
  const int srb = tid >> 2;
  const int sbb = (tid & 3) * 2;     // slot base after bf16 conversion (2 slots)
  const float* bsrc = (srb < 128)
      ? wg + ((size_t)e * ID + nt * 128 + srb) * HD + (tid & 3) * 16
      : wu + ((size_t)e * ID + nt * 128 + (srb - 128)) * HD + (tid & 3) * 16;

  f32x4 accg[4][4] = {};
  f32x4 accu[4][4] = {};
  u16x8 ra[4];
  f32x4 rb[4];

#define G1_LOAD(kt)                                                       \
  do {                                                                    \
    const unsigned short* a_ = asrc + (kt) * 64;                          \
    const float* b_ = bsrc + (kt) * 64;                                   \
    _Pragma("unroll") for (int i = 0; i < 4; ++i) ra[i] = *(const u16x8*)(a_ + i * 8); \
    _Pragma("unroll") for (int i = 0; i < 4; ++i) rb[i] = *(const f32x4*)(b_ + i * 4); \
  } while (0)

#define G1_WRITE()                                                        \
  do {                                                                    \
    _Pragma("unroll") for (int i = 0; i < 4; ++i)                         \
      *(u16x8*)(lds + AADDR(sra, sba + i)) = ra[i];                       \
    _Pragma("unroll") for (int i = 0; i < 2; ++i)                         \
      *(bf16x8*)(lds + BADDR(srb, sbb + i)) = pack8(rb[2 * i], rb[2 * i + 1]); \
  } while (0)

  const int NIT = HD / 64;
  G1_LOAD(0);

  for (int ks = 0; ks < NIT; ++ks) {
    G1_WRITE();              // vmcnt wait lands here; covered by previous compute phase
    bar_lgkm();
    if (ks + 1 < NIT) G1_LOAD(ks + 1);
#pragma unroll
    for (int sub = 0; sub < 2; ++sub) {
      bf16x8 a[4], bg[4], bu[4];
#pragma unroll
      for (int mi = 0; mi < 4; ++mi)
        a[mi] = *(const bf16x8*)(lds + AADDR(wm * 64 + mi * 16 + frow, sub * 4 + fk));
#pragma unroll
      for (int ni = 0; ni < 4; ++ni) {
        bg[ni] = *(const bf16x8*)(lds + BADDR(wn * 64 + ni * 16 + frow, sub * 4 + fk));
        bu[ni] = *(const bf16x8*)(lds + BADDR(128 + wn * 64 + ni * 16 + frow, sub * 4 + fk));
      }
      __builtin_amdgcn_s_setprio(1);
#pragma unroll
      for (int mi = 0; mi < 4; ++mi)
#pragma unroll
        for (int ni = 0; ni < 4; ++ni) {
          accg[mi][ni] = __builtin_amdgcn_mfma_f32_16x16x32_bf16(a[mi], bg[ni], accg[mi][ni], 0, 0, 0);
          accu[mi][ni] = __builtin_amdgcn_mfma_f32_16x16x32_bf16(a[mi], bu[ni], accu[mi][ni], 0, 0, 0);
        }
      __builtin_amdgcn_s_setprio(0);
    }
    bar_lgkm();
  }
#undef G1_LOAD
#undef G1_WRITE

  // lane-local gelu fusion epilogue (no exchange needed)
#pragma unroll
  for (int mi = 0; mi < 4; ++mi)
#pragma unroll
    for (int j = 0; j < 4; ++j) {
      const int grow = mt * 512 + wm * 64 + mi * 16 + fk * 4 + j;
      if (grow < ne) {
        unsigned short* hrow = hidden + (size_t)(off + grow) * ID + nt * 128 + wn * 64;
#pragma unroll
        for (int ni = 0; ni < 4; ++ni) {
          __bf16 hb = (__bf16)(gelu_tanh(accg[mi][ni][j]) * accu[mi][ni][j]);
          hrow[ni * 16 + frow] = __builtin_bit_cast(unsigned short, hb);
        }
      }
    }
}

// out[token,:] = hidden[p,:] @ wd[e]^T; round-3 structure (proven): 512 thr, 8 waves (2Mx4N),
// wave tile 64x32, BK=64, single-buf LDS + reg prefetch + non-draining barriers.
__global__ __launch_bounds__(512, 2) void gemm2_k(
    const unsigned short* __restrict__ hidden, const float* __restrict__ wd,
    const int* __restrict__ perm, const int* __restrict__ counts,
    const int* __restrict__ offsets, float* __restrict__ out) {
  const int e = blockIdx.z, mt = blockIdx.y, nt = blockIdx.x;
  const int ne = counts[e];
  if (mt * 128 >= ne) return;
  const int off = offsets[e];

  __shared__ unsigned short la[128 * LS];
  __shared__ unsigned short lb[128 * LS];

  const int tid = threadIdx.x;
  const int lane = tid & 63;
  const int wid = tid >> 6;
  const int wrow = (wid >> 2) * 64;
  const int wcol = (wid & 3) * 32;
  const int sc = tid & 7;
  const int sr = tid >> 3;

  const unsigned short* ap[2];
#pragma unroll
  for (int rd = 0; rd < 2; ++rd) {
    int lr = mt * 128 + sr + 64 * rd;
    int gr = off + ((lr < ne) ? lr : (ne - 1));  // clamp: stay inside hidden
    ap[rd] = hidden + (size_t)gr * ID + sc * 8;
  }
  const float* bp0 = wd + ((size_t)e * HD + nt * 128 + sr) * ID + sc * 8;

  f32x4 acc[4][2] = {};
  u16x8 rawa[2];
  f32x4 rb[2][2];

#define LOADT2(k0)                                                        \
  do {                                                                    \
    _Pragma("unroll") for (int rd = 0; rd < 2; ++rd) {                    \
      rawa[rd] = *(const u16x8*)(ap[rd] + (k0));                          \
      const float* b_ = bp0 + (size_t)rd * 64 * ID + (k0);                \
      rb[rd][0] = *(const f32x4*)b_; rb[rd][1] = *(const f32x4*)(b_ + 4); \
    }                                                                     \
  } while (0)

  LOADT2(0);
  const int frow = lane & 15, fko = (lane >> 4) * 8;

  for (int ks = 0; ks < ID / 64; ++ks) {
#pragma unroll
    for (int rd = 0; rd < 2; ++rd) {
      const int wa = (sr + 64 * rd) * LS + sc * 8;
      *(u16x8*)(la + wa) = rawa[rd];
      *(bf16x8*)(lb + wa) = pack8(rb[rd][0], rb[rd][1]);
    }
    bar_lgkm();
    if (ks + 1 < ID / 64) LOADT2((ks + 1) * 64);
#pragma unroll
    for (int kk = 0; kk < 2; ++kk) {
      const int kb = kk * 32 + fko;
      bf16x8 a[4], b[2];
#pragma unroll
      for (int mi = 0; mi < 4; ++mi)
        a[mi] = *(const bf16x8*)(la + (wrow + mi * 16 + frow) * LS + kb);
#pragma unroll
      for (int ni = 0; ni < 2; ++ni)
        b[ni] = *(const bf16x8*)(lb + (wcol + ni * 16 + frow) * LS + kb);
      __builtin_amdgcn_s_setprio(1);
#pragma unroll
      for (int mi = 0; mi < 4; ++mi)
#pragma unroll
        for (int ni = 0; ni < 2; ++ni)
          acc[mi][ni] = __builtin_amdgcn_mfma_f32_16x16x32_bf16(a[mi], b[ni], acc[mi][ni], 0, 0, 0);
      __builtin_amdgcn_s_setprio(0);
    }
    bar_lgkm();
  }
#undef LOADT2

  const int colb = nt * 128 + wcol + (lane & 15);
#pragma unroll
  for (int mi = 0; mi < 4; ++mi) {
#pragma unroll
    for (int j = 0; j < 4; ++j) {
      const int grow = mt * 128 + wrow + mi * 16 + ((lane >> 4) << 2) + j;
      if (grow < ne) {
        const int t = perm[off + grow];
        float* orow = out + (size_t)t * HD + colb;
#pragma unroll
        for (int ni = 0; ni < 2; ++ni) orow[ni * 16] = acc[mi][ni][j];
      }
    }
  }
}

extern "C" void kernel_launch(void* const* d_in, const int* in_sizes, int n_in,
                              void* d_out, int out_size, void* d_ws, size_t ws_size,
                              hipStream_t stream) {
  const float* x  = (const float*)d_in[0];
  const float* gw = (const float*)d_in[1];
  const float* wg = (const float*)d_in[2];
  const float* wu = (const float*)d_in[3];
  const float* wd = (const float*)d_in[4];
  float* out = (float*)d_out;
  float* logits = out + (size_t)TOK * HD;

  unsigned short* hidden = (unsigned short*)d_ws;                       // 33.55 MB
  unsigned short* xp = (unsigned short*)((char*)d_ws + 33554432);       // 8.39 MB
  int* meta = (int*)((char*)d_ws + 33554432 + 8388608);
  int* counts  = meta;        // [8]
  int* counts2 = meta + 8;    // [8]
  int* offsets = meta + 16;   // [8]
  int* top1    = meta + 24;   // [TOK]
  int* perm    = meta + 24 + TOK;  // [TOK]

  init_k<<<1, 64, 0, stream>>>(meta);
  router_k<<<TOK / 4, 256, 0, stream>>>(x, gw, logits, top1);
  hist_k<<<TOK / 256, 256, 0, stream>>>(top1, counts);
  offsets_k<<<1, 64, 0, stream>>>(counts, offsets);
  scatter_k<<<TOK / 256, 256, 0, stream>>>(top1, offsets, counts2, perm);
  xp_k<<<TOK / 4, 256, 0, stream>>>(x, perm, xp);
  gemm1_k<<<dim3(ID / 128, 8, NE), 1024, 0, stream>>>(xp, wg, wu, counts, offsets, hidden);
  gemm2_k<<<dim3(HD / 128, TOK / 128, NE), 512, 0, stream>>>(hidden, wd, perm, counts, offsets, out);
}

// Round 7
// 866.530 us; speedup vs baseline: 2.1361x; 2.1361x over previous
//
#include <hip/hip_runtime.h>

#define TOK 4096
#define HD 1024
#define ID 4096
#define NE 8

typedef __attribute__((ext_vector_type(4))) float f32x4;
typedef __attribute__((ext_vector_type(8))) __bf16 bf16x8;
typedef __attribute__((ext_vector_type(8))) unsigned short u16x8;

// LDS rows are 64B (BK=32 bf16) = 4 x 16B slots; swizzle slot s -> s ^ ((row>>1)&3).
// 16 lanes reading same slot across rows r..r+15 spread over all 4 slot-groups (2-way = free).
#define SSW(r, s) ((((s) ^ (((r) >> 1) & 3))) << 4)

// compiler emits v_cvt_pk_bf16_f32 (RNE) for scalar casts -- do NOT hand-roll (m240)
__device__ __forceinline__ bf16x8 pack8(f32x4 a, f32x4 b) {
  bf16x8 r;
#pragma unroll
  for (int i = 0; i < 4; ++i) { r[i] = (__bf16)a[i]; r[i + 4] = (__bf16)b[i]; }
  return r;
}

__device__ __forceinline__ float gelu_tanh(float g) {
  float z = 0.7978845608028654f * (g + 0.044715f * g * g * g);
  float t = __expf(-2.0f * z);
  return g / (1.0f + t);
}

// barrier that does NOT drain vmcnt: LDS ordering via lgkmcnt(0), global prefetch stays in flight
__device__ __forceinline__ void bar_lgkm() {
  asm volatile("s_waitcnt lgkmcnt(0)" ::: "memory");
  __builtin_amdgcn_s_barrier();
}

__global__ void init_k(int* __restrict__ meta) {
  if (threadIdx.x < 16) meta[threadIdx.x] = 0;
}

// one wave per token: fp32 logits (argmax must match numpy fp32), top1 via first-max
__global__ void router_k(const float* __restrict__ x, const float* __restrict__ gw,
                         float* __restrict__ logits, int* __restrict__ top1) {
  const int wid = threadIdx.x >> 6;
  const int lane = threadIdx.x & 63;
  const int t = blockIdx.x * 4 + wid;
  const float* xr = x + (size_t)t * HD;
  float acc[NE];
#pragma unroll
  for (int e = 0; e < NE; ++e) acc[e] = 0.0f;
#pragma unroll
  for (int c = 0; c < 4; ++c) {
    const int k = (c * 64 + lane) * 4;
    f32x4 xv = *(const f32x4*)(xr + k);
#pragma unroll
    for (int e = 0; e < NE; ++e) {
      f32x4 gv = *(const f32x4*)(gw + e * HD + k);
      acc[e] += xv[0] * gv[0] + xv[1] * gv[1] + xv[2] * gv[2] + xv[3] * gv[3];
    }
  }
#pragma unroll
  for (int off = 32; off > 0; off >>= 1) {
#pragma unroll
    for (int e = 0; e < NE; ++e) acc[e] += __shfl_xor(acc[e], off, 64);
  }
  if (lane == 0) {
    int best = 0; float bv = acc[0];
#pragma unroll
    for (int e = 1; e < NE; ++e) if (acc[e] > bv) { bv = acc[e]; best = e; }
    top1[t] = best;
#pragma unroll
    for (int e = 0; e < NE; ++e) logits[(size_t)t * NE + e] = acc[e];
  }
}

__global__ void hist_k(const int* __restrict__ top1, int* __restrict__ counts) {
  int t = blockIdx.x * 256 + threadIdx.x;
  atomicAdd(&counts[top1[t]], 1);
}

__global__ void offsets_k(const int* __restrict__ counts, int* __restrict__ offsets) {
  if (threadIdx.x == 0) {
    int s = 0;
    for (int e = 0; e < NE; ++e) { offsets[e] = s; s += counts[e]; }
  }
}

__global__ void scatter_k(const int* __restrict__ top1, const int* __restrict__ offsets,
                          int* __restrict__ counts2, int* __restrict__ perm) {
  int t = blockIdx.x * 256 + threadIdx.x;
  int e = top1[t];
  int slot = atomicAdd(&counts2[e], 1);
  perm[offsets[e] + slot] = t;
}

// compact permuted bf16 copy of x: xp[p,:] = bf16(x[perm[p],:])
__global__ void xp_k(const float* __restrict__ x, const int* __restrict__ perm,
                     unsigned short* __restrict__ xp) {
  const int p = blockIdx.x * 4 + (threadIdx.x >> 6);
  const int lane = threadIdx.x & 63;
  const float* src = x + (size_t)perm[p] * HD + lane * 16;
  unsigned short* dst = xp + (size_t)p * HD + lane * 16;
  f32x4 v0 = *(const f32x4*)(src);
  f32x4 v1 = *(const f32x4*)(src + 4);
  f32x4 v2 = *(const f32x4*)(src + 8);
  f32x4 v3 = *(const f32x4*)(src + 12);
  *(bf16x8*)(dst) = pack8(v0, v1);
  *(bf16x8*)(dst + 8) = pack8(v2, v3);
}

// gemm1: BM=128 tok x 128 out-cols, B-LDS = 256 rows (128 gate + 128 up), BK=32.
// 512 thr / 8 waves = 2wm x {wn0,1=gate | wn2,3=up}, wave 64x64, acc 4x4.
// dbuf LDS + depth-2 reg prefetch, parity-unrolled (compile-time buf indices),
// one lgkm-barrier per tile. Fusion via LDS exchange epilogue.
__global__ __launch_bounds__(512, 4) void gemm1_k(
    const unsigned short* __restrict__ xp, const float* __restrict__ wg,
    const float* __restrict__ wu, const int* __restrict__ counts,
    const int* __restrict__ offsets, unsigned short* __restrict__ hidden) {
  const int bid = blockIdx.x;
  const int en = bid & 255;          // (e,nt): mt-siblings share XCD (same bid%8)
  const int mt = bid >> 8;
  const int e = en >> 5, nt = en & 31;
  const int ne = counts[e];
  if (mt * 128 >= ne) return;
  const int off = offsets[e];

  __shared__ __align__(16) char lds[67584];  // tiles: A 2x8K @0, B 2x16K @16384; epilogue ex 128x132 f32

  const int tid = threadIdx.x;
  const int lane = tid & 63;
  const int wid = tid >> 6;
  const int wm = wid >> 2;            // 0..1
  const int wn = wid & 3;             // 0,1 gate | 2,3 up
  const int wrow = wm * 64;
  const int frow = lane & 15;
  const int fk = lane >> 4;           // 0..3 slot
  const int brow0 = (wn < 2) ? wn * 64 : 128 + (wn - 2) * 64;

  // A staging: 4 thr/row, 16B each. row=tid>>2, slot=tid&3
  const int ar = tid >> 2, as = tid & 3;
  int tokrow = off + mt * 128 + ar;
  if (tokrow >= TOK) tokrow = TOK - 1;           // masked at store
  const unsigned short* asrc = xp + (size_t)tokrow * HD + as * 8;

  // B staging: 2 thr/row, 64B fp32 each. row=tid>>1 (0-127 gate,128-255 up), half=tid&1
  const int br = tid >> 1, bh = tid & 1;
  const float* bsrc = (br < 128)
      ? wg + ((size_t)e * ID + nt * 128 + br) * HD + bh * 16
      : wu + ((size_t)e * ID + nt * 128 + (br - 128)) * HD + bh * 16;
  const int bs0 = (2 * bh) ^ ((br >> 1) & 3);
  const int bs1 = (2 * bh + 1) ^ ((br >> 1) & 3);

  f32x4 acc[4][4] = {};
  u16x8 rAv[2];
  f32x4 rBv[2][4];

#define G1_LOAD(kt, p)                                                   \
  do {                                                                   \
    rAv[p] = *(const u16x8*)(asrc + (kt) * 32);                          \
    const float* b_ = bsrc + (kt) * 32;                                  \
    _Pragma("unroll") for (int i = 0; i < 4; ++i)                        \
      rBv[p][i] = *(const f32x4*)(b_ + i * 4);                           \
  } while (0)

#define G1_WRITE(p)                                                      \
  do {                                                                   \
    *(u16x8*)(lds + (p) * 8192 + ar * 64 + SSW(ar, as)) = rAv[p];        \
    *(bf16x8*)(lds + 16384 + (p) * 16384 + br * 64 + (bs0 << 4)) = pack8(rBv[p][0], rBv[p][1]); \
    *(bf16x8*)(lds + 16384 + (p) * 16384 + br * 64 + (bs1 << 4)) = pack8(rBv[p][2], rBv[p][3]); \
  } while (0)

#define G1_COMPUTE(p)                                                    \
  do {                                                                   \
    bf16x8 af[4], bb[4];                                                 \
    _Pragma("unroll") for (int mi = 0; mi < 4; ++mi) {                   \
      const int r_ = wrow + mi * 16 + frow;                              \
      af[mi] = *(const bf16x8*)(lds + (p) * 8192 + r_ * 64 + SSW(r_, fk)); \
    }                                                                    \
    _Pragma("unroll") for (int ni = 0; ni < 4; ++ni) {                   \
      const int r_ = brow0 + ni * 16 + frow;                             \
      bb[ni] = *(const bf16x8*)(lds + 16384 + (p) * 16384 + r_ * 64 + SSW(r_, fk)); \
    }                                                                    \
    __builtin_amdgcn_s_setprio(1);                                       \
    _Pragma("unroll") for (int mi = 0; mi < 4; ++mi)                     \
      _Pragma("unroll") for (int ni = 0; ni < 4; ++ni)                   \
        acc[mi][ni] = __builtin_amdgcn_mfma_f32_16x16x32_bf16(af[mi], bb[ni], acc[mi][ni], 0, 0, 0); \
    __builtin_amdgcn_s_setprio(0);                                       \
  } while (0)

  const int NIT = HD / 32;  // 32
  G1_LOAD(0, 0);
  G1_LOAD(1, 1);
  for (int ks = 0; ks < NIT; ks += 2) {
    G1_WRITE(0);                       // auto-waits only its own vmcnt (issued 2 tiles ago)
    bar_lgkm();
    if (ks + 2 < NIT) G1_LOAD(ks + 2, 0);
    G1_COMPUTE(0);
    G1_WRITE(1);
    bar_lgkm();
    if (ks + 3 < NIT) G1_LOAD(ks + 3, 1);
    G1_COMPUTE(1);
  }
#undef G1_LOAD
#undef G1_WRITE
#undef G1_COMPUTE

  // epilogue: gate waves -> LDS exchange; up waves fuse gelu(g)*u -> hidden bf16
  __syncthreads();
  float* ex = (float*)lds;  // [128][132]
  if (wn < 2) {
#pragma unroll
    for (int mi = 0; mi < 4; ++mi)
#pragma unroll
      for (int ni = 0; ni < 4; ++ni)
#pragma unroll
        for (int j = 0; j < 4; ++j) {
          const int row = wrow + mi * 16 + fk * 4 + j;
          ex[row * 132 + wn * 64 + ni * 16 + frow] = acc[mi][ni][j];
        }
  }
  __syncthreads();
  if (wn >= 2) {
#pragma unroll
    for (int mi = 0; mi < 4; ++mi)
#pragma unroll
      for (int j = 0; j < 4; ++j) {
        const int row = wrow + mi * 16 + fk * 4 + j;
        const int grow = mt * 128 + row;
        if (grow < ne) {
          unsigned short* hrow = hidden + (size_t)(off + grow) * ID + nt * 128 + (wn - 2) * 64;
#pragma unroll
          for (int ni = 0; ni < 4; ++ni) {
            float g = ex[row * 132 + (wn - 2) * 64 + ni * 16 + frow];
            __bf16 hb = (__bf16)(gelu_tanh(g) * acc[mi][ni][j]);
            hrow[ni * 16 + frow] = __builtin_bit_cast(unsigned short, hb);
          }
        }
      }
  }
}

// gemm2: out[token] = hidden[p] @ wd[e]^T. BM=128 x BN=128, BK=32, 256 thr / 4 waves (2x2),
// wave 64x64 acc 4x4. Same dbuf + depth-2 prefetch + 1 barrier/tile structure.
__global__ __launch_bounds__(256, 4) void gemm2_k(
    const unsigned short* __restrict__ hidden, const float* __restrict__ wd,
    const int* __restrict__ perm, const int* __restrict__ counts,
    const int* __restrict__ offsets, float* __restrict__ out) {
  const int bid = blockIdx.x;
  const int en = bid & 63;           // (e,nt): mt-siblings share XCD
  const int mt = bid >> 6;
  const int e = en >> 3, nt = en & 7;
  const int ne = counts[e];
  if (mt * 128 >= ne) return;
  const int off = offsets[e];

  __shared__ __align__(16) char lds[32768];  // A 2x8K @0, B 2x8K @16384

  const int tid = threadIdx.x;
  const int lane = tid & 63;
  const int wid = tid >> 6;
  const int wm = wid >> 1, wn = wid & 1;
  const int wrow = wm * 64, wcol = wn * 64;
  const int frow = lane & 15;
  const int fk = lane >> 4;

  // A: 2 thr/row, 32B bf16 each. row=tid>>1, half=tid&1 -> slots 2h,2h+1
  const int ar = tid >> 1, ah = tid & 1;
  int lrA = mt * 128 + ar;
  const unsigned short* asrc = hidden + (size_t)(off + ((lrA < ne) ? lrA : (ne - 1))) * ID + ah * 16;
  const int as0 = (2 * ah) ^ ((ar >> 1) & 3);
  const int as1 = (2 * ah + 1) ^ ((ar >> 1) & 3);

  // B: 2 thr/row, 64B fp32 each. row=tid>>1, half=tid&1
  const float* bsrc = wd + ((size_t)e * HD + nt * 128 + ar) * ID + ah * 16;

  f32x4 acc[4][4] = {};
  u16x8 rA2[2][2];
  f32x4 rB2[2][4];

#define G2_LOAD(kt, p)                                                   \
  do {                                                                   \
    rA2[p][0] = *(const u16x8*)(asrc + (kt) * 32);                       \
    rA2[p][1] = *(const u16x8*)(asrc + (kt) * 32 + 8);                   \
    const float* b_ = bsrc + (kt) * 32;                                  \
    _Pragma("unroll") for (int i = 0; i < 4; ++i)                        \
      rB2[p][i] = *(const f32x4*)(b_ + i * 4);                           \
  } while (0)

#define G2_WRITE(p)                                                      \
  do {                                                                   \
    *(u16x8*)(lds + (p) * 8192 + ar * 64 + (as0 << 4)) = rA2[p][0];      \
    *(u16x8*)(lds + (p) * 8192 + ar * 64 + (as1 << 4)) = rA2[p][1];      \
    *(bf16x8*)(lds + 16384 + (p) * 8192 + ar * 64 + (as0 << 4)) = pack8(rB2[p][0], rB2[p][1]); \
    *(bf16x8*)(lds + 16384 + (p) * 8192 + ar * 64 + (as1 << 4)) = pack8(rB2[p][2], rB2[p][3]); \
  } while (0)

#define G2_COMPUTE(p)                                                    \
  do {                                                                   \
    bf16x8 af[4], bb[4];                                                 \
    _Pragma("unroll") for (int mi = 0; mi < 4; ++mi) {                   \
      const int r_ = wrow + mi * 16 + frow;                              \
      af[mi] = *(const bf16x8*)(lds + (p) * 8192 + r_ * 64 + SSW(r_, fk)); \
    }                                                                    \
    _Pragma("unroll") for (int ni = 0; ni < 4; ++ni) {                   \
      const int r_ = wcol + ni * 16 + frow;                              \
      bb[ni] = *(const bf16x8*)(lds + 16384 + (p) * 8192 + r_ * 64 + SSW(r_, fk)); \
    }                                                                    \
    __builtin_amdgcn_s_setprio(1);                                       \
    _Pragma("unroll") for (int mi = 0; mi < 4; ++mi)                     \
      _Pragma("unroll") for (int ni = 0; ni < 4; ++ni)                   \
        acc[mi][ni] = __builtin_amdgcn_mfma_f32_16x16x32_bf16(af[mi], bb[ni], acc[mi][ni], 0, 0, 0); \
    __builtin_amdgcn_s_setprio(0);                                       \
  } while (0)

  const int NIT = ID / 32;  // 128
  G2_LOAD(0, 0);
  G2_LOAD(1, 1);
  for (int ks = 0; ks < NIT; ks += 2) {
    G2_WRITE(0);
    bar_lgkm();
    if (ks + 2 < NIT) G2_LOAD(ks + 2, 0);
    G2_COMPUTE(0);
    G2_WRITE(1);
    bar_lgkm();
    if (ks + 3 < NIT) G2_LOAD(ks + 3, 1);
    G2_COMPUTE(1);
  }
#undef G2_LOAD
#undef G2_WRITE
#undef G2_COMPUTE

#pragma unroll
  for (int mi = 0; mi < 4; ++mi)
#pragma unroll
    for (int j = 0; j < 4; ++j) {
      const int row = wrow + mi * 16 + fk * 4 + j;
      const int grow = mt * 128 + row;
      if (grow < ne) {
        const int t = perm[off + grow];
        float* orow = out + (size_t)t * HD + nt * 128 + wcol;
#pragma unroll
        for (int ni = 0; ni < 4; ++ni) orow[ni * 16 + frow] = acc[mi][ni][j];
      }
    }
}

extern "C" void kernel_launch(void* const* d_in, const int* in_sizes, int n_in,
                              void* d_out, int out_size, void* d_ws, size_t ws_size,
                              hipStream_t stream) {
  const float* x  = (const float*)d_in[0];
  const float* gw = (const float*)d_in[1];
  const float* wg = (const float*)d_in[2];
  const float* wu = (const float*)d_in[3];
  const float* wd = (const float*)d_in[4];
  float* out = (float*)d_out;
  float* logits = out + (size_t)TOK * HD;

  unsigned short* hidden = (unsigned short*)d_ws;                       // 33.55 MB
  unsigned short* xp = (unsigned short*)((char*)d_ws + 33554432);       // 8.39 MB
  int* meta = (int*)((char*)d_ws + 33554432 + 8388608);
  int* counts  = meta;        // [8]
  int* counts2 = meta + 8;    // [8]
  int* offsets = meta + 16;   // [8]
  int* top1    = meta + 24;   // [TOK]
  int* perm    = meta + 24 + TOK;  // [TOK]

  init_k<<<1, 64, 0, stream>>>(meta);
  router_k<<<TOK / 4, 256, 0, stream>>>(x, gw, logits, top1);
  hist_k<<<TOK / 256, 256, 0, stream>>>(top1, counts);
  offsets_k<<<1, 64, 0, stream>>>(counts, offsets);
  scatter_k<<<TOK / 256, 256, 0, stream>>>(top1, offsets, counts2, perm);
  xp_k<<<TOK / 4, 256, 0, stream>>>(x, perm, xp);
  gemm1_k<<<256 * (TOK / 128), 512, 0, stream>>>(xp, wg, wu, counts, offsets, hidden);
  gemm2_k<<<64 * (TOK / 128), 256, 0, stream>>>(hidden, wd, perm, counts, offsets, out);
}

// Round 8
// 397.866 us; speedup vs baseline: 4.6524x; 2.1779x over previous
//
#include <hip/hip_runtime.h>

#define TOK 4096
#define HD 1024
#define ID 4096
#define NE 8

typedef __attribute__((ext_vector_type(4))) float f32x4;
typedef __attribute__((ext_vector_type(8))) __bf16 bf16x8;
typedef __attribute__((ext_vector_type(8))) unsigned short u16x8;

// LDS rows are 64B (BK=32 bf16) = 4 x 16B slots; swizzle slot s -> s ^ ((row>>1)&3).
#define SSW(r, s) ((((s) ^ (((r) >> 1) & 3))) << 4)

// compiler emits v_cvt_pk_bf16_f32 (RNE) for scalar casts -- do NOT hand-roll (m240)
__device__ __forceinline__ bf16x8 pack8(f32x4 a, f32x4 b) {
  bf16x8 r;
#pragma unroll
  for (int i = 0; i < 4; ++i) { r[i] = (__bf16)a[i]; r[i + 4] = (__bf16)b[i]; }
  return r;
}

__device__ __forceinline__ float gelu_tanh(float g) {
  float z = 0.7978845608028654f * (g + 0.044715f * g * g * g);
  float t = __expf(-2.0f * z);
  return g / (1.0f + t);
}

// barrier that does NOT drain vmcnt: LDS ordering via lgkmcnt(0), global prefetch stays in flight
__device__ __forceinline__ void bar_lgkm() {
  asm volatile("s_waitcnt lgkmcnt(0)" ::: "memory");
  __builtin_amdgcn_s_barrier();
}

__global__ void init_k(int* __restrict__ meta) {
  if (threadIdx.x < 16) meta[threadIdx.x] = 0;
}

// one wave per token: fp32 logits (argmax must match numpy fp32), top1 via first-max
__global__ void router_k(const float* __restrict__ x, const float* __restrict__ gw,
                         float* __restrict__ logits, int* __restrict__ top1) {
  const int wid = threadIdx.x >> 6;
  const int lane = threadIdx.x & 63;
  const int t = blockIdx.x * 4 + wid;
  const float* xr = x + (size_t)t * HD;
  float acc[NE];
#pragma unroll
  for (int e = 0; e < NE; ++e) acc[e] = 0.0f;
#pragma unroll
  for (int c = 0; c < 4; ++c) {
    const int k = (c * 64 + lane) * 4;
    f32x4 xv = *(const f32x4*)(xr + k);
#pragma unroll
    for (int e = 0; e < NE; ++e) {
      f32x4 gv = *(const f32x4*)(gw + e * HD + k);
      acc[e] += xv[0] * gv[0] + xv[1] * gv[1] + xv[2] * gv[2] + xv[3] * gv[3];
    }
  }
#pragma unroll
  for (int off = 32; off > 0; off >>= 1) {
#pragma unroll
    for (int e = 0; e < NE; ++e) acc[e] += __shfl_xor(acc[e], off, 64);
  }
  if (lane == 0) {
    int best = 0; float bv = acc[0];
#pragma unroll
    for (int e = 1; e < NE; ++e) if (acc[e] > bv) { bv = acc[e]; best = e; }
    top1[t] = best;
#pragma unroll
    for (int e = 0; e < NE; ++e) logits[(size_t)t * NE + e] = acc[e];
  }
}

__global__ void hist_k(const int* __restrict__ top1, int* __restrict__ counts) {
  int t = blockIdx.x * 256 + threadIdx.x;
  atomicAdd(&counts[top1[t]], 1);
}

__global__ void offsets_k(const int* __restrict__ counts, int* __restrict__ offsets) {
  if (threadIdx.x == 0) {
    int s = 0;
    for (int e = 0; e < NE; ++e) { offsets[e] = s; s += counts[e]; }
  }
}

__global__ void scatter_k(const int* __restrict__ top1, const int* __restrict__ offsets,
                          int* __restrict__ counts2, int* __restrict__ perm) {
  int t = blockIdx.x * 256 + threadIdx.x;
  int e = top1[t];
  int slot = atomicAdd(&counts2[e], 1);
  perm[offsets[e] + slot] = t;
}

// compact permuted bf16 copy of x: xp[p,:] = bf16(x[perm[p],:])
__global__ void xp_k(const float* __restrict__ x, const int* __restrict__ perm,
                     unsigned short* __restrict__ xp) {
  const int p = blockIdx.x * 4 + (threadIdx.x >> 6);
  const int lane = threadIdx.x & 63;
  const float* src = x + (size_t)perm[p] * HD + lane * 16;
  unsigned short* dst = xp + (size_t)p * HD + lane * 16;
  f32x4 v0 = *(const f32x4*)(src);
  f32x4 v1 = *(const f32x4*)(src + 4);
  f32x4 v2 = *(const f32x4*)(src + 8);
  f32x4 v3 = *(const f32x4*)(src + 12);
  *(bf16x8*)(dst) = pack8(v0, v1);
  *(bf16x8*)(dst + 8) = pack8(v2, v3);
}

// gemm1: BM=128 tok x 128 out-cols, B-LDS = 256 rows (128 gate + 128 up), BK=32.
// 512 thr / 8 waves = 2wm x {wn0,1=gate | wn2,3=up}, wave 64x64, acc 4x4.
// dbuf LDS + depth-2 reg prefetch, parity-unrolled, one lgkm-barrier per tile.
// launch_bounds(512,2): reg cap 256 -> acc(64 AGPR)+~110 VGPR fits, NO SPILL (R7 lesson).
__global__ __launch_bounds__(512, 2) void gemm1_k(
    const unsigned short* __restrict__ xp, const float* __restrict__ wg,
    const float* __restrict__ wu, const int* __restrict__ counts,
    const int* __restrict__ offsets, unsigned short* __restrict__ hidden) {
  const int bid = blockIdx.x;
  const int en = bid & 255;          // (e,nt): mt-siblings share XCD (same bid%8)
  const int mt = bid >> 8;
  const int e = en >> 5, nt = en & 31;
  const int ne = counts[e];
  if (mt * 128 >= ne) return;
  const int off = offsets[e];

  __shared__ __align__(16) char lds[67584];  // tiles: A 2x8K @0, B 2x16K @16384; epilogue ex 128x132 f32

  const int tid = threadIdx.x;
  const int lane = tid & 63;
  const int wid = tid >> 6;
  const int wm = wid >> 2;            // 0..1
  const int wn = wid & 3;             // 0,1 gate | 2,3 up
  const int wrow = wm * 64;
  const int frow = lane & 15;
  const int fk = lane >> 4;           // 0..3 slot
  const int brow0 = (wn < 2) ? wn * 64 : 128 + (wn - 2) * 64;

  // A staging: 4 thr/row, 16B each. row=tid>>2, slot=tid&3
  const int ar = tid >> 2, as = tid & 3;
  int tokrow = off + mt * 128 + ar;
  if (tokrow >= TOK) tokrow = TOK - 1;           // masked at store
  const unsigned short* asrc = xp + (size_t)tokrow * HD + as * 8;

  // B staging: 2 thr/row, 64B fp32 each. row=tid>>1 (0-127 gate,128-255 up), half=tid&1
  const int br = tid >> 1, bh = tid & 1;
  const float* bsrc = (br < 128)
      ? wg + ((size_t)e * ID + nt * 128 + br) * HD + bh * 16
      : wu + ((size_t)e * ID + nt * 128 + (br - 128)) * HD + bh * 16;
  const int bs0 = (2 * bh) ^ ((br >> 1) & 3);
  const int bs1 = (2 * bh + 1) ^ ((br >> 1) & 3);

  f32x4 acc[4][4] = {};
  u16x8 rAv[2];
  f32x4 rBv[2][4];

#define G1_LOAD(kt, p)                                                   \
  do {                                                                   \
    rAv[p] = *(const u16x8*)(asrc + (kt) * 32);                          \
    const float* b_ = bsrc + (kt) * 32;                                  \
    _Pragma("unroll") for (int i = 0; i < 4; ++i)                        \
      rBv[p][i] = *(const f32x4*)(b_ + i * 4);                           \
  } while (0)

#define G1_WRITE(p)                                                      \
  do {                                                                   \
    *(u16x8*)(lds + (p) * 8192 + ar * 64 + SSW(ar, as)) = rAv[p];        \
    *(bf16x8*)(lds + 16384 + (p) * 16384 + br * 64 + (bs0 << 4)) = pack8(rBv[p][0], rBv[p][1]); \
    *(bf16x8*)(lds + 16384 + (p) * 16384 + br * 64 + (bs1 << 4)) = pack8(rBv[p][2], rBv[p][3]); \
  } while (0)

#define G1_COMPUTE(p)                                                    \
  do {                                                                   \
    bf16x8 af[4], bb[4];                                                 \
    _Pragma("unroll") for (int mi = 0; mi < 4; ++mi) {                   \
      const int r_ = wrow + mi * 16 + frow;                              \
      af[mi] = *(const bf16x8*)(lds + (p) * 8192 + r_ * 64 + SSW(r_, fk)); \
    }                                                                    \
    _Pragma("unroll") for (int ni = 0; ni < 4; ++ni) {                   \
      const int r_ = brow0 + ni * 16 + frow;                             \
      bb[ni] = *(const bf16x8*)(lds + 16384 + (p) * 16384 + r_ * 64 + SSW(r_, fk)); \
    }                                                                    \
    __builtin_amdgcn_s_setprio(1);                                       \
    _Pragma("unroll") for (int mi = 0; mi < 4; ++mi)                     \
      _Pragma("unroll") for (int ni = 0; ni < 4; ++ni)                   \
        acc[mi][ni] = __builtin_amdgcn_mfma_f32_16x16x32_bf16(af[mi], bb[ni], acc[mi][ni], 0, 0, 0); \
    __builtin_amdgcn_s_setprio(0);                                       \
  } while (0)

  const int NIT = HD / 32;  // 32
  G1_LOAD(0, 0);
  G1_LOAD(1, 1);
  for (int ks = 0; ks < NIT; ks += 2) {
    G1_WRITE(0);                       // auto-waits only its own vmcnt (issued 2 tiles ago)
    bar_lgkm();
    if (ks + 2 < NIT) G1_LOAD(ks + 2, 0);
    G1_COMPUTE(0);
    G1_WRITE(1);
    bar_lgkm();
    if (ks + 3 < NIT) G1_LOAD(ks + 3, 1);
    G1_COMPUTE(1);
  }
#undef G1_LOAD
#undef G1_WRITE
#undef G1_COMPUTE

  // epilogue: gate waves -> LDS exchange; up waves fuse gelu(g)*u -> hidden bf16
  __syncthreads();
  float* ex = (float*)lds;  // [128][132]
  if (wn < 2) {
#pragma unroll
    for (int mi = 0; mi < 4; ++mi)
#pragma unroll
      for (int ni = 0; ni < 4; ++ni)
#pragma unroll
        for (int j = 0; j < 4; ++j) {
          const int row = wrow + mi * 16 + fk * 4 + j;
          ex[row * 132 + wn * 64 + ni * 16 + frow] = acc[mi][ni][j];
        }
  }
  __syncthreads();
  if (wn >= 2) {
#pragma unroll
    for (int mi = 0; mi < 4; ++mi)
#pragma unroll
      for (int j = 0; j < 4; ++j) {
        const int row = wrow + mi * 16 + fk * 4 + j;
        const int grow = mt * 128 + row;
        if (grow < ne) {
          unsigned short* hrow = hidden + (size_t)(off + grow) * ID + nt * 128 + (wn - 2) * 64;
#pragma unroll
          for (int ni = 0; ni < 4; ++ni) {
            float g = ex[row * 132 + (wn - 2) * 64 + ni * 16 + frow];
            __bf16 hb = (__bf16)(gelu_tanh(g) * acc[mi][ni][j]);
            hrow[ni * 16 + frow] = __builtin_bit_cast(unsigned short, hb);
          }
        }
      }
  }
}

// gemm2: out[token] = hidden[p] @ wd[e]^T. BM=128 x BN=128, BK=32, 256 thr / 4 waves (2x2),
// wave 64x64 acc 4x4. Same dbuf + depth-2 prefetch + 1 barrier/tile structure.
__global__ __launch_bounds__(256, 2) void gemm2_k(
    const unsigned short* __restrict__ hidden, const float* __restrict__ wd,
    const int* __restrict__ perm, const int* __restrict__ counts,
    const int* __restrict__ offsets, float* __restrict__ out) {
  const int bid = blockIdx.x;
  const int en = bid & 63;           // (e,nt): mt-siblings share XCD
  const int mt = bid >> 6;
  const int e = en >> 3, nt = en & 7;
  const int ne = counts[e];
  if (mt * 128 >= ne) return;
  const int off = offsets[e];

  __shared__ __align__(16) char lds[32768];  // A 2x8K @0, B 2x8K @16384

  const int tid = threadIdx.x;
  const int lane = tid & 63;
  const int wid = tid >> 6;
  const int wm = wid >> 1, wn = wid & 1;
  const int wrow = wm * 64, wcol = wn * 64;
  const int frow = lane & 15;
  const int fk = lane >> 4;

  // A: 2 thr/row, 32B bf16 each. row=tid>>1, half=tid&1 -> slots 2h,2h+1
  const int ar = tid >> 1, ah = tid & 1;
  int lrA = mt * 128 + ar;
  const unsigned short* asrc = hidden + (size_t)(off + ((lrA < ne) ? lrA : (ne - 1))) * ID + ah * 16;
  const int as0 = (2 * ah) ^ ((ar >> 1) & 3);
  const int as1 = (2 * ah + 1) ^ ((ar >> 1) & 3);

  // B: 2 thr/row, 64B fp32 each. row=tid>>1, half=tid&1
  const float* bsrc = wd + ((size_t)e * HD + nt * 128 + ar) * ID + ah * 16;

  f32x4 acc[4][4] = {};
  u16x8 rA2[2][2];
  f32x4 rB2[2][4];

#define G2_LOAD(kt, p)                                                   \
  do {                                                                   \
    rA2[p][0] = *(const u16x8*)(asrc + (kt) * 32);                       \
    rA2[p][1] = *(const u16x8*)(asrc + (kt) * 32 + 8);                   \
    const float* b_ = bsrc + (kt) * 32;                                  \
    _Pragma("unroll") for (int i = 0; i < 4; ++i)                        \
      rB2[p][i] = *(const f32x4*)(b_ + i * 4);                           \
  } while (0)

#define G2_WRITE(p)                                                      \
  do {                                                                   \
    *(u16x8*)(lds + (p) * 8192 + ar * 64 + (as0 << 4)) = rA2[p][0];      \
    *(u16x8*)(lds + (p) * 8192 + ar * 64 + (as1 << 4)) = rA2[p][1];      \
    *(bf16x8*)(lds + 16384 + (p) * 8192 + ar * 64 + (as0 << 4)) = pack8(rB2[p][0], rB2[p][1]); \
    *(bf16x8*)(lds + 16384 + (p) * 8192 + ar * 64 + (as1 << 4)) = pack8(rB2[p][2], rB2[p][3]); \
  } while (0)

#define G2_COMPUTE(p)                                                    \
  do {                                                                   \
    bf16x8 af[4], bb[4];                                                 \
    _Pragma("unroll") for (int mi = 0; mi < 4; ++mi) {                   \
      const int r_ = wrow + mi * 16 + frow;                              \
      af[mi] = *(const bf16x8*)(lds + (p) * 8192 + r_ * 64 + SSW(r_, fk)); \
    }                                                                    \
    _Pragma("unroll") for (int ni = 0; ni < 4; ++ni) {                   \
      const int r_ = wcol + ni * 16 + frow;                              \
      bb[ni] = *(const bf16x8*)(lds + 16384 + (p) * 8192 + r_ * 64 + SSW(r_, fk)); \
    }                                                                    \
    __builtin_amdgcn_s_setprio(1);                                       \
    _Pragma("unroll") for (int mi = 0; mi < 4; ++mi)                     \
      _Pragma("unroll") for (int ni = 0; ni < 4; ++ni)                   \
        acc[mi][ni] = __builtin_amdgcn_mfma_f32_16x16x32_bf16(af[mi], bb[ni], acc[mi][ni], 0, 0, 0); \
    __builtin_amdgcn_s_setprio(0);                                       \
  } while (0)

  const int NIT = ID / 32;  // 128
  G2_LOAD(0, 0);
  G2_LOAD(1, 1);
  for (int ks = 0; ks < NIT; ks += 2) {
    G2_WRITE(0);
    bar_lgkm();
    if (ks + 2 < NIT) G2_LOAD(ks + 2, 0);
    G2_COMPUTE(0);
    G2_WRITE(1);
    bar_lgkm();
    if (ks + 3 < NIT) G2_LOAD(ks + 3, 1);
    G2_COMPUTE(1);
  }
#undef G2_LOAD
#undef G2_WRITE
#undef G2_COMPUTE

#pragma unroll
  for (int mi = 0; mi < 4; ++mi)
#pragma unroll
    for (int j = 0; j < 4; ++j) {
      const int row = wrow + mi * 16 + fk * 4 + j;
      const int grow = mt * 128 + row;
      if (grow < ne) {
        const int t = perm[off + grow];
        float* orow = out + (size_t)t * HD + nt * 128 + wcol;
#pragma unroll
        for (int ni = 0; ni < 4; ++ni) orow[ni * 16 + frow] = acc[mi][ni][j];
      }
    }
}

extern "C" void kernel_launch(void* const* d_in, const int* in_sizes, int n_in,
                              void* d_out, int out_size, void* d_ws, size_t ws_size,
                              hipStream_t stream) {
  const float* x  = (const float*)d_in[0];
  const float* gw = (const float*)d_in[1];
  const float* wg = (const float*)d_in[2];
  const float* wu = (const float*)d_in[3];
  const float* wd = (const float*)d_in[4];
  float* out = (float*)d_out;
  float* logits = out + (size_t)TOK * HD;

  unsigned short* hidden = (unsigned short*)d_ws;                       // 33.55 MB
  unsigned short* xp = (unsigned short*)((char*)d_ws + 33554432);       // 8.39 MB
  int* meta = (int*)((char*)d_ws + 33554432 + 8388608);
  int* counts  = meta;        // [8]
  int* counts2 = meta + 8;    // [8]
  int* offsets = meta + 16;   // [8]
  int* top1    = meta + 24;   // [TOK]
  int* perm    = meta + 24 + TOK;  // [TOK]

  init_k<<<1, 64, 0, stream>>>(meta);
  router_k<<<TOK / 4, 256, 0, stream>>>(x, gw, logits, top1);
  hist_k<<<TOK / 256, 256, 0, stream>>>(top1, counts);
  offsets_k<<<1, 64, 0, stream>>>(counts, offsets);
  scatter_k<<<TOK / 256, 256, 0, stream>>>(top1, offsets, counts2, perm);
  xp_k<<<TOK / 4, 256, 0, stream>>>(x, perm, xp);
  gemm1_k<<<256 * (TOK / 128), 512, 0, stream>>>(xp, wg, wu, counts, offsets, hidden);
  gemm2_k<<<64 * (TOK / 128), 256, 0, stream>>>(hidden, wd, perm, counts, offsets, out);
}